// Round 5
// baseline (142.398 us; speedup 1.0000x reference)
//
#include <hip/hip_runtime.h>
#include <math.h>

// TransformDomainInterpolator — split FFT / stream-out version.
//
// Math (verified R3/R4, absmax 0.0156):
//   even[m] = in_r[b, s*2048+m] (exact);
//   odd = IDFT_2048( t_k * DFT_2048(x_s) )/2048, t_k = ±e^{i pi k/2048};
//   out[b,t,4q..4q+3] = [lerp(e 2q), lerp(o 2q), lerp(e 2q+1), lerp(o 2q+1)],
//   lerp weight w=[0,0, 0/9..8/9, 1,1,1] over 14 symbols (real parts only).
//
// Kernel A: 1024 blocks x 256 thr, one (batch,symbol) FFT per block.
//   Register-radix-8 (3 radix-2 stages per LDS phase), 6 barriers; final
//   inverse phase stores Re(odd) straight from registers to d_ws.
// Kernel B: 1024 blocks x 256 thr, block = (batch, 7-symbol half);
//   pure streaming lerp+store, reads are L3-hot (in_r 8.4MB + ws 8.4MB).

#define NSC  4096
#define PI_F 3.14159265358979323846f

__device__ __forceinline__ int pada(int i) { return i + 2 * (i >> 5); }

__device__ __forceinline__ void bf_fwd(float2& a, float2& c, float tc, float ts) {
  const float tx = a.x - c.x, ty = a.y - c.y;
  a.x += c.x; a.y += c.y;
  c.x = tx * tc - ty * ts;
  c.y = tx * ts + ty * tc;
}
__device__ __forceinline__ void bf_inv(float2& a, float2& c, float tc, float ts) {
  const float tx = c.x * tc - c.y * ts, ty = c.x * ts + c.y * tc;
  c.x = a.x - tx; c.y = a.y - ty;
  a.x += tx; a.y += ty;
}

// ---------------------------------------------------------------- kernel A
__global__ __launch_bounds__(256)
void tdi_fft(const float* __restrict__ in_r,
             const float* __restrict__ in_i,
             float* __restrict__ ws_odd) {      // [batch*2][2048] Re(odd)
  __shared__ __align__(16) float2 As[2176];     // 2048 + pad

  const int u   = threadIdx.x;                  // 0..255
  const int bid = blockIdx.x;                   // b*2 + sym
  const int b   = bid >> 1;
  const int sym = bid & 1;

  const float* __restrict__ pr = in_r + ((size_t)b << 12) + (sym << 11);
  const float* __restrict__ pm = in_i + ((size_t)b << 12) + (sym << 11);

  float2 x[8];
  float s, c;

  // -------- F1: load + forward stages 10,9,8 (idx = u + 256j) ------------
#pragma unroll
  for (int j = 0; j < 8; ++j)
    x[j] = make_float2(pr[u + 256 * j], pm[u + 256 * j]);
#pragma unroll
  for (int j = 0; j < 4; ++j) {                 // stage 10: pos = u+256j
    __sincosf((float)(u + 256 * j) * (PI_F / 1024.f), &s, &c);
    bf_fwd(x[j], x[j + 4], c, -s);
  }
  {                                             // stage 9: pos = u+256*(j&1)
    float s0, c0, s1, c1;
    __sincosf((float)u * (PI_F / 512.f), &s0, &c0);
    __sincosf((float)(u + 256) * (PI_F / 512.f), &s1, &c1);
    bf_fwd(x[0], x[2], c0, -s0); bf_fwd(x[1], x[3], c1, -s1);
    bf_fwd(x[4], x[6], c0, -s0); bf_fwd(x[5], x[7], c1, -s1);
  }
  __sincosf((float)u * (PI_F / 256.f), &s, &c); // stage 8: pos = u
  bf_fwd(x[0], x[1], c, -s); bf_fwd(x[2], x[3], c, -s);
  bf_fwd(x[4], x[5], c, -s); bf_fwd(x[6], x[7], c, -s);
#pragma unroll
  for (int j = 0; j < 8; ++j) As[pada(u + 256 * j)] = x[j];
  __syncthreads();

  // -------- F2: stages 7,6,5 (idx = (u>>5)*256 + (u&31) + 32j) -----------
  {
    const int q = u & 31;
    const int base = ((u >> 5) << 8) | q;
#pragma unroll
    for (int j = 0; j < 8; ++j) x[j] = As[pada(base + 32 * j)];
#pragma unroll
    for (int j = 0; j < 4; ++j) {               // stage 7: pos = q+32j
      __sincosf((float)(q + 32 * j) * (PI_F / 128.f), &s, &c);
      bf_fwd(x[j], x[j + 4], c, -s);
    }
    float s0, c0, s1, c1;                       // stage 6: pos = q+32*(j&1)
    __sincosf((float)q * (PI_F / 64.f), &s0, &c0);
    __sincosf((float)(q + 32) * (PI_F / 64.f), &s1, &c1);
    bf_fwd(x[0], x[2], c0, -s0); bf_fwd(x[1], x[3], c1, -s1);
    bf_fwd(x[4], x[6], c0, -s0); bf_fwd(x[5], x[7], c1, -s1);
    __sincosf((float)q * (PI_F / 32.f), &s, &c);// stage 5: pos = q
    bf_fwd(x[0], x[1], c, -s); bf_fwd(x[2], x[3], c, -s);
    bf_fwd(x[4], x[5], c, -s); bf_fwd(x[6], x[7], c, -s);
#pragma unroll
    for (int j = 0; j < 8; ++j) As[pada(base + 32 * j)] = x[j];
  }
  __syncthreads();

  // -------- F3: stages 4,3,2 (idx = (u>>2)*32 + (u&3) + 4j) --------------
  {
    const int q = u & 3;
    const int base = ((u >> 2) << 5) | q;
#pragma unroll
    for (int j = 0; j < 8; ++j) x[j] = As[pada(base + 4 * j)];
#pragma unroll
    for (int j = 0; j < 4; ++j) {               // stage 4: pos = q+4j
      __sincosf((float)(q + 4 * j) * (PI_F / 16.f), &s, &c);
      bf_fwd(x[j], x[j + 4], c, -s);
    }
    float s0, c0, s1, c1;                       // stage 3: pos = q+4*(j&1)
    __sincosf((float)q * (PI_F / 8.f), &s0, &c0);
    __sincosf((float)(q + 4) * (PI_F / 8.f), &s1, &c1);
    bf_fwd(x[0], x[2], c0, -s0); bf_fwd(x[1], x[3], c1, -s1);
    bf_fwd(x[4], x[6], c0, -s0); bf_fwd(x[5], x[7], c1, -s1);
    __sincosf((float)q * (PI_F / 4.f), &s, &c); // stage 2: pos = q
    bf_fwd(x[0], x[1], c, -s); bf_fwd(x[2], x[3], c, -s);
    bf_fwd(x[4], x[5], c, -s); bf_fwd(x[6], x[7], c, -s);
#pragma unroll
    for (int j = 0; j < 8; ++j) As[pada(base + 4 * j)] = x[j];
  }
  __syncthreads();

  // -------- F4: fwd 1,0 + pointwise + inv 0,1 (idx = 8u+j) ---------------
  {
    const int base = u << 3;
#pragma unroll
    for (int j = 0; j < 8; ++j) x[j] = As[pada(base + j)];
    // fwd stage 1: tw=1 for (0,2),(4,6); tw=-i for (1,3),(5,7)
#pragma unroll
    for (int g = 0; g < 8; g += 4) {
      float2 t;
      t.x = x[g].x - x[g+2].x;  t.y = x[g].y - x[g+2].y;
      x[g].x += x[g+2].x;       x[g].y += x[g+2].y;
      x[g+2] = t;
      t.x = x[g+1].x - x[g+3].x; t.y = x[g+1].y - x[g+3].y;
      x[g+1].x += x[g+3].x;      x[g+1].y += x[g+3].y;
      x[g+3] = make_float2(t.y, -t.x);          // * (-i)
    }
    // fwd stage 0: tw=1
#pragma unroll
    for (int g = 0; g < 8; g += 2) {
      float2 t;
      t.x = x[g].x - x[g+1].x; t.y = x[g].y - x[g+1].y;
      x[g].x += x[g+1].x;      x[g].y += x[g+1].y;
      x[g+1] = t;
    }
    // pointwise half-sample-shift filter (+1/2048), bit-reversed order
#pragma unroll
    for (int j = 0; j < 8; ++j) {
      const int p = base + j;
      const int k = (int)(__brev((unsigned)p) >> 21);
      const float sc = (k >= 1024) ? -(1.f / 2048.f) : (1.f / 2048.f);
      __sincosf((float)k * (PI_F / 2048.f), &s, &c);
      const float fc = c * sc, fs = s * sc;
      const float2 a = x[j];
      x[j] = make_float2(a.x * fc - a.y * fs, a.x * fs + a.y * fc);
    }
    // inv stage 0: tw=1
#pragma unroll
    for (int g = 0; g < 8; g += 2) {
      const float2 t = x[g+1];
      x[g+1].x = x[g].x - t.x; x[g+1].y = x[g].y - t.y;
      x[g].x  += t.x;          x[g].y  += t.y;
    }
    // inv stage 1: tw=1 for (0,2),(4,6); tw=+i for (1,3),(5,7)
#pragma unroll
    for (int g = 0; g < 8; g += 4) {
      float2 t = x[g+2];
      x[g+2].x = x[g].x - t.x; x[g+2].y = x[g].y - t.y;
      x[g].x  += t.x;          x[g].y  += t.y;
      t = make_float2(-x[g+3].y, x[g+3].x);     // * (+i)
      x[g+3].x = x[g+1].x - t.x; x[g+3].y = x[g+1].y - t.y;
      x[g+1].x += t.x;           x[g+1].y += t.y;
    }
#pragma unroll
    for (int j = 0; j < 8; ++j) As[pada(base + j)] = x[j];
  }
  __syncthreads();

  // -------- I2: inv stages 2,3,4 (footprint of F3) -----------------------
  {
    const int q = u & 3;
    const int base = ((u >> 2) << 5) | q;
#pragma unroll
    for (int j = 0; j < 8; ++j) x[j] = As[pada(base + 4 * j)];
    __sincosf((float)q * (PI_F / 4.f), &s, &c); // stage 2
    bf_inv(x[0], x[1], c, s); bf_inv(x[2], x[3], c, s);
    bf_inv(x[4], x[5], c, s); bf_inv(x[6], x[7], c, s);
    float s0, c0, s1, c1;                       // stage 3
    __sincosf((float)q * (PI_F / 8.f), &s0, &c0);
    __sincosf((float)(q + 4) * (PI_F / 8.f), &s1, &c1);
    bf_inv(x[0], x[2], c0, s0); bf_inv(x[1], x[3], c1, s1);
    bf_inv(x[4], x[6], c0, s0); bf_inv(x[5], x[7], c1, s1);
#pragma unroll
    for (int j = 0; j < 4; ++j) {               // stage 4
      __sincosf((float)(q + 4 * j) * (PI_F / 16.f), &s, &c);
      bf_inv(x[j], x[j + 4], c, s);
    }
#pragma unroll
    for (int j = 0; j < 8; ++j) As[pada(base + 4 * j)] = x[j];
  }
  __syncthreads();

  // -------- I3: inv stages 5,6,7 (footprint of F2) -----------------------
  {
    const int q = u & 31;
    const int base = ((u >> 5) << 8) | q;
#pragma unroll
    for (int j = 0; j < 8; ++j) x[j] = As[pada(base + 32 * j)];
    __sincosf((float)q * (PI_F / 32.f), &s, &c);// stage 5
    bf_inv(x[0], x[1], c, s); bf_inv(x[2], x[3], c, s);
    bf_inv(x[4], x[5], c, s); bf_inv(x[6], x[7], c, s);
    float s0, c0, s1, c1;                       // stage 6
    __sincosf((float)q * (PI_F / 64.f), &s0, &c0);
    __sincosf((float)(q + 32) * (PI_F / 64.f), &s1, &c1);
    bf_inv(x[0], x[2], c0, s0); bf_inv(x[1], x[3], c1, s1);
    bf_inv(x[4], x[6], c0, s0); bf_inv(x[5], x[7], c1, s1);
#pragma unroll
    for (int j = 0; j < 4; ++j) {               // stage 7
      __sincosf((float)(q + 32 * j) * (PI_F / 128.f), &s, &c);
      bf_inv(x[j], x[j + 4], c, s);
    }
#pragma unroll
    for (int j = 0; j < 8; ++j) As[pada(base + 32 * j)] = x[j];
  }
  __syncthreads();

  // -------- I4: inv stages 8,9,10 (idx = u + 256j) -> global Re stores ---
  {
#pragma unroll
    for (int j = 0; j < 8; ++j) x[j] = As[pada(u + 256 * j)];
    __sincosf((float)u * (PI_F / 256.f), &s, &c); // stage 8
    bf_inv(x[0], x[1], c, s); bf_inv(x[2], x[3], c, s);
    bf_inv(x[4], x[5], c, s); bf_inv(x[6], x[7], c, s);
    float s0, c0, s1, c1;                         // stage 9
    __sincosf((float)u * (PI_F / 512.f), &s0, &c0);
    __sincosf((float)(u + 256) * (PI_F / 512.f), &s1, &c1);
    bf_inv(x[0], x[2], c0, s0); bf_inv(x[1], x[3], c1, s1);
    bf_inv(x[4], x[6], c0, s0); bf_inv(x[5], x[7], c1, s1);
#pragma unroll
    for (int j = 0; j < 4; ++j) {                 // stage 10
      __sincosf((float)(u + 256 * j) * (PI_F / 1024.f), &s, &c);
      bf_inv(x[j], x[j + 4], c, s);
    }
    float* __restrict__ wrow = ws_odd + ((size_t)bid << 11);
#pragma unroll
    for (int j = 0; j < 8; ++j) wrow[u + 256 * j] = x[j].x;
  }
}

// ---------------------------------------------------------------- kernel B
__global__ __launch_bounds__(256)
void tdi_lerp(const float* __restrict__ in_r,
              const float* __restrict__ ws_odd,
              float4* __restrict__ out) {
  const int bid  = blockIdx.x;        // b*2 + half
  const int b    = bid >> 1;
  const int half = bid & 1;
  const int tid  = threadIdx.x;

  const float* __restrict__ er = in_r  + ((size_t)b << 12);
  const float* __restrict__ od = ws_odd + ((size_t)b << 12);

  float2 e0[4], e1[4], o0[4], o1[4];
#pragma unroll
  for (int k = 0; k < 4; ++k) {
    const int q = tid + (k << 8);     // float4 index within row, 0..1023
    e0[k] = *(const float2*)&er[2 * q];
    e1[k] = *(const float2*)&er[2048 + 2 * q];
    o0[k] = *(const float2*)&od[2 * q];
    o1[k] = *(const float2*)&od[2048 + 2 * q];
  }

  float4* __restrict__ orow = out + ((size_t)b * 14 + half * 7) * 1024;
  for (int ti = 0; ti < 7; ++ti) {
    const int t = half * 7 + ti;
    const float w = (t < 2) ? 0.f : (t >= 11) ? 1.f
                     : (float)(t - 2) * (1.f / 9.f);
#pragma unroll
    for (int k = 0; k < 4; ++k) {
      const int q = tid + (k << 8);
      float4 v;
      v.x = e0[k].x + w * (e1[k].x - e0[k].x);
      v.y = o0[k].x + w * (o1[k].x - o0[k].x);
      v.z = e0[k].y + w * (e1[k].y - e0[k].y);
      v.w = o0[k].y + w * (o1[k].y - o0[k].y);
      orow[ti * 1024 + q] = v;
    }
  }
}

extern "C" void kernel_launch(void* const* d_in, const int* in_sizes, int n_in,
                              void* d_out, int out_size, void* d_ws, size_t ws_size,
                              hipStream_t stream) {
  const float* hr = (const float*)d_in[0];
  const float* hi = (const float*)d_in[1];
  const int batch = in_sizes[0] / NSC;          // 512 for the reference config
  float* ws = (float*)d_ws;                     // needs batch*4096*4 B = 8.4 MB
  tdi_fft <<<dim3(batch * 2), dim3(256), 0, stream>>>(hr, hi, ws);
  tdi_lerp<<<dim3(batch * 2), dim3(256), 0, stream>>>(hr, ws, (float4*)d_out);
}

// Round 6
// 131.664 us; speedup vs baseline: 1.0815x; 1.0815x over previous
//
#include <hip/hip_runtime.h>
#include <math.h>

// TransformDomainInterpolator — fused register-radix-8 FFT, rotation-derived
// twiddles (R4 structure + 50->7 sincos reduction; R5 split regressed -> refused).
//
// Math (verified R3/R4, absmax 0.0156):
//   even[m] = in_r[b, s*2048+m] (exact)
//   odd = IDFT_2048( t_k * DFT_2048(x_s) )/2048, t_k = ±e^{i pi k/2048}
//   out[b,t,4q..4q+3] = [lerp(e 2q), lerp(o 2q), lerp(e 2q+1), lerp(o 2q+1)],
//   lerp w=[0,0, 0/9..8/9, 1,1,1] over 14 symbols (real parts only).
//
// 512 thr/block, one batch/block; threads 0-255 symbol 0, 256-511 symbol 1.
// 7 LDS phases; per phase ONE sincos + exact constant rotations:
//   stage A: e^{-i(th+j*pi/4)} — multiply by e^{-ij*pi/4} constants
//   stage B: 2th and 2th+pi/2 — double-angle
//   stage C: 4th — double-angle again
// Pointwise: k*pi/2048 = rev8(u)*pi/2048 + rev3(j)*pi/8 (pi/8 table).

#define NSC  4096
#define PI_F 3.14159265358979323846f
#define RSQ2 0.70710678118654752f

__device__ __forceinline__ int pada(int i) { return i + 2 * (i >> 5); }

__device__ __forceinline__ void bf_fwd(float2& a, float2& c, float tc, float ts) {
  const float tx = a.x - c.x, ty = a.y - c.y;
  a.x += c.x; a.y += c.y;
  c.x = tx * tc - ty * ts;
  c.y = tx * ts + ty * tc;
}
__device__ __forceinline__ void bf_inv(float2& a, float2& c, float tc, float ts) {
  const float tx = c.x * tc - c.y * ts, ty = c.x * ts + c.y * tc;
  c.x = a.x - tx; c.y = a.y - ty;
  a.x += tx; a.y += ty;
}

// Forward 3-stage block: pairs (j,j+4) tw e^{-i(th+j pi/4)}; (j,j+2) tw
// e^{-i 2th} / e^{-i(2th+pi/2)}; (j,j+1) tw e^{-i 4th}.  (c,s)=sincos(th).
__device__ __forceinline__ void fwd3(float2* x, float c, float s) {
  bf_fwd(x[0], x[4], c, -s);
  { const float cj = RSQ2 * (c - s), sj = RSQ2 * (c + s);
    bf_fwd(x[1], x[5], cj, -sj); }
  bf_fwd(x[2], x[6], -s, -c);
  { const float cj = -RSQ2 * (s + c), sj = RSQ2 * (c - s);
    bf_fwd(x[3], x[7], cj, -sj); }
  const float c2 = c * c - s * s, s2 = 2.f * c * s;
  bf_fwd(x[0], x[2], c2, -s2);  bf_fwd(x[4], x[6], c2, -s2);
  bf_fwd(x[1], x[3], -s2, -c2); bf_fwd(x[5], x[7], -s2, -c2);
  const float c4 = c2 * c2 - s2 * s2, s4 = 2.f * c2 * s2;
  bf_fwd(x[0], x[1], c4, -s4); bf_fwd(x[2], x[3], c4, -s4);
  bf_fwd(x[4], x[5], c4, -s4); bf_fwd(x[6], x[7], c4, -s4);
}

// Inverse 3-stage block (stages low->high): (j,j+1) e^{+i4th}; (j,j+2)
// e^{+i2th}/e^{+i(2th+pi/2)}; (j,j+4) e^{+i(th+j pi/4)}.
__device__ __forceinline__ void inv3(float2* x, float c, float s) {
  const float c2 = c * c - s * s, s2 = 2.f * c * s;
  const float c4 = c2 * c2 - s2 * s2, s4 = 2.f * c2 * s2;
  bf_inv(x[0], x[1], c4, s4); bf_inv(x[2], x[3], c4, s4);
  bf_inv(x[4], x[5], c4, s4); bf_inv(x[6], x[7], c4, s4);
  bf_inv(x[0], x[2], c2, s2);  bf_inv(x[4], x[6], c2, s2);
  bf_inv(x[1], x[3], -s2, c2); bf_inv(x[5], x[7], -s2, c2);
  bf_inv(x[0], x[4], c, s);
  { const float cj = RSQ2 * (c - s), sj = RSQ2 * (c + s);
    bf_inv(x[1], x[5], cj, sj); }
  bf_inv(x[2], x[6], -s, c);
  { const float cj = -RSQ2 * (s + c), sj = RSQ2 * (c - s);
    bf_inv(x[3], x[7], cj, sj); }
}

__global__ __launch_bounds__(512)
void tdi_fft_interp(const float* __restrict__ in_r,
                    const float* __restrict__ in_i,
                    float4* __restrict__ out) {
  __shared__ __align__(16) float2 A[2][2176];   // 2048 + pad per symbol

  const int tid = threadIdx.x;
  const int b   = blockIdx.x;
  const int u   = tid & 255;    // thread index within a symbol's FFT
  const int sym = tid >> 8;     // 0 or 1
  float2* __restrict__ As = A[sym];

  const float* __restrict__ pr = in_r + ((size_t)b << 12) + (sym << 11);
  const float* __restrict__ pm = in_i + ((size_t)b << 12) + (sym << 11);

  float2 x[8];
  float s, c;

  // ---- F1: load + forward stages 10,9,8 (idx = u + 256j), th = u*pi/1024
#pragma unroll
  for (int j = 0; j < 8; ++j)
    x[j] = make_float2(pr[u + 256 * j], pm[u + 256 * j]);
  __sincosf((float)u * (PI_F / 1024.f), &s, &c);
  fwd3(x, c, s);
#pragma unroll
  for (int j = 0; j < 8; ++j) As[pada(u + 256 * j)] = x[j];
  __syncthreads();

  // ---- F2: stages 7,6,5 (idx = (u>>5)*256 + (u&31) + 32j), th = q*pi/128
  {
    const int q = u & 31;
    const int base = ((u >> 5) << 8) | q;
#pragma unroll
    for (int j = 0; j < 8; ++j) x[j] = As[pada(base + 32 * j)];
    __sincosf((float)q * (PI_F / 128.f), &s, &c);
    fwd3(x, c, s);
#pragma unroll
    for (int j = 0; j < 8; ++j) As[pada(base + 32 * j)] = x[j];
  }
  __syncthreads();

  // ---- F3: stages 4,3,2 (idx = (u>>2)*32 + (u&3) + 4j), th = q*pi/16
  {
    const int q = u & 3;
    const int base = ((u >> 2) << 5) | q;
#pragma unroll
    for (int j = 0; j < 8; ++j) x[j] = As[pada(base + 4 * j)];
    __sincosf((float)q * (PI_F / 16.f), &s, &c);
    fwd3(x, c, s);
#pragma unroll
    for (int j = 0; j < 8; ++j) As[pada(base + 4 * j)] = x[j];
  }
  __syncthreads();

  // ---- F4: fwd stages 1,0 + pointwise + inv stages 0,1 (idx = 8u+j) -----
  {
    const int base = u << 3;
#pragma unroll
    for (int j = 0; j < 8; ++j) x[j] = As[pada(base + j)];
    // fwd stage 1: tw=1 for (0,2),(4,6); tw=-i for (1,3),(5,7)
#pragma unroll
    for (int g = 0; g < 8; g += 4) {
      float2 t;
      t.x = x[g].x - x[g+2].x;  t.y = x[g].y - x[g+2].y;
      x[g].x += x[g+2].x;       x[g].y += x[g+2].y;
      x[g+2] = t;
      t.x = x[g+1].x - x[g+3].x; t.y = x[g+1].y - x[g+3].y;
      x[g+1].x += x[g+3].x;      x[g+1].y += x[g+3].y;
      x[g+3] = make_float2(t.y, -t.x);          // * (-i)
    }
    // fwd stage 0: tw=1
#pragma unroll
    for (int g = 0; g < 8; g += 2) {
      float2 t;
      t.x = x[g].x - x[g+1].x; t.y = x[g].y - x[g+1].y;
      x[g].x += x[g+1].x;      x[g].y += x[g+1].y;
      x[g+1] = t;
    }
    // pointwise filter: angle = rev8(u)*pi/2048 + rev3(j)*pi/8,
    // sign = (j odd ? -1 : +1), scale 1/2048
    {
      const float c8[8] = { 1.f,  0.92387953f,  0.70710678f,  0.38268343f,
                            0.f, -0.38268343f, -0.70710678f, -0.92387953f };
      const float s8[8] = { 0.f,  0.38268343f,  0.70710678f,  0.92387953f,
                            1.f,  0.92387953f,  0.70710678f,  0.38268343f };
      float cp, sp;
      __sincosf((float)(__brev((unsigned)u) >> 24) * (PI_F / 2048.f), &sp, &cp);
#pragma unroll
      for (int j = 0; j < 8; ++j) {
        const int rv = ((j & 1) << 2) | (j & 2) | (j >> 2);
        const float sc = (j & 1) ? -(1.f / 2048.f) : (1.f / 2048.f);
        const float fc = (cp * c8[rv] - sp * s8[rv]) * sc;
        const float fs = (sp * c8[rv] + cp * s8[rv]) * sc;
        const float2 a = x[j];
        x[j] = make_float2(a.x * fc - a.y * fs, a.x * fs + a.y * fc);
      }
    }
    // inv stage 0: tw=1
#pragma unroll
    for (int g = 0; g < 8; g += 2) {
      const float2 t = x[g+1];
      x[g+1].x = x[g].x - t.x; x[g+1].y = x[g].y - t.y;
      x[g].x  += t.x;          x[g].y  += t.y;
    }
    // inv stage 1: tw=1 for (0,2),(4,6); tw=+i for (1,3),(5,7)
#pragma unroll
    for (int g = 0; g < 8; g += 4) {
      float2 t = x[g+2];
      x[g+2].x = x[g].x - t.x; x[g+2].y = x[g].y - t.y;
      x[g].x  += t.x;          x[g].y  += t.y;
      t = make_float2(-x[g+3].y, x[g+3].x);     // * (+i)
      x[g+3].x = x[g+1].x - t.x; x[g+3].y = x[g+1].y - t.y;
      x[g+1].x += t.x;           x[g+1].y += t.y;
    }
#pragma unroll
    for (int j = 0; j < 8; ++j) As[pada(base + j)] = x[j];
  }
  __syncthreads();

  // ---- I2: inv stages 2,3,4 (footprint of F3), th = q*pi/16 --------------
  {
    const int q = u & 3;
    const int base = ((u >> 2) << 5) | q;
#pragma unroll
    for (int j = 0; j < 8; ++j) x[j] = As[pada(base + 4 * j)];
    __sincosf((float)q * (PI_F / 16.f), &s, &c);
    inv3(x, c, s);
#pragma unroll
    for (int j = 0; j < 8; ++j) As[pada(base + 4 * j)] = x[j];
  }
  __syncthreads();

  // ---- I3: inv stages 5,6,7 (footprint of F2), th = q*pi/128 -------------
  {
    const int q = u & 31;
    const int base = ((u >> 5) << 8) | q;
#pragma unroll
    for (int j = 0; j < 8; ++j) x[j] = As[pada(base + 32 * j)];
    __sincosf((float)q * (PI_F / 128.f), &s, &c);
    inv3(x, c, s);
#pragma unroll
    for (int j = 0; j < 8; ++j) As[pada(base + 32 * j)] = x[j];
  }
  __syncthreads();

  // ---- I4: inv stages 8,9,10 (idx = u + 256j), th = u*pi/1024 ------------
  {
#pragma unroll
    for (int j = 0; j < 8; ++j) x[j] = As[pada(u + 256 * j)];
    __sincosf((float)u * (PI_F / 1024.f), &s, &c);
    inv3(x, c, s);
#pragma unroll
    for (int j = 0; j < 8; ++j) As[pada(u + 256 * j)] = x[j];
  }
  __syncthreads();

  // ---- Epilogue: lerp over 14 symbols, float4 stores ---------------------
  float2 E0[2], E1[2], O0[2], O1[2];
  const float* __restrict__ er0 = in_r + ((size_t)b << 12);
  const float* __restrict__ er1 = er0 + 2048;
#pragma unroll
  for (int e = 0; e < 2; ++e) {
    const int q = tid + e * 512;
    E0[e] = *(const float2*)&er0[2 * q];
    E1[e] = *(const float2*)&er1[2 * q];
    const float4 a0 = *(const float4*)&A[0][pada(2 * q)];
    const float4 a1 = *(const float4*)&A[1][pada(2 * q)];
    O0[e] = make_float2(a0.x, a0.z);
    O1[e] = make_float2(a1.x, a1.z);
  }
  float4* __restrict__ orow = out + (size_t)b * 14 * 1024;
  for (int t = 0; t < 14; ++t) {
    const float w = (t < 2) ? 0.f : (t >= 11) ? 1.f : (float)(t - 2) * (1.f / 9.f);
#pragma unroll
    for (int e = 0; e < 2; ++e) {
      const int q = tid + e * 512;
      float4 v;
      v.x = E0[e].x + w * (E1[e].x - E0[e].x);
      v.y = O0[e].x + w * (O1[e].x - O0[e].x);
      v.z = E0[e].y + w * (E1[e].y - E0[e].y);
      v.w = O0[e].y + w * (O1[e].y - O0[e].y);
      orow[t * 1024 + q] = v;
    }
  }
}

extern "C" void kernel_launch(void* const* d_in, const int* in_sizes, int n_in,
                              void* d_out, int out_size, void* d_ws, size_t ws_size,
                              hipStream_t stream) {
  const float* hr = (const float*)d_in[0];
  const float* hi = (const float*)d_in[1];
  const int batch = in_sizes[0] / NSC;   // 512 for the reference config
  tdi_fft_interp<<<dim3(batch), dim3(512), 0, stream>>>(hr, hi, (float4*)d_out);
}